// Round 4
// baseline (300.265 us; speedup 1.0000x reference)
//
#include <hip/hip_runtime.h>

// TurboQuant round-trip, replicating numpy float32 semantics bit-exactly so
// quantization argmin decisions match the harness's np (fp32) reference:
//  - norm: x*x separately rounded (fp contract OFF), numpy pairwise-8 scalar
//    summation order, IEEE sqrt (via fp64 then cast).
//  - xs = x / scale: IEEE RN fp32 division (via fp64 divide then cast).
//  - z_j = <xs, R[j,:]>: sequential-k single-chain fmaf (OpenBLAS sgemm
//    micro-kernel accumulation order).
//  - argmin over |z - cb[i]| in fp32, first-index ties (numpy argmin).
// Reconstruction (z_hat @ R) * scale in fp32 (order-insensitive at tol).

#define TQ_D 64
#define TQ_NLEV 16

__global__ __launch_bounds__(256) void tq_f32(
    const float* __restrict__ x,
    const float* __restrict__ cbk,
    const float* __restrict__ R,
    float* __restrict__ out,
    int nrows)
{
#pragma clang fp contract(off)
    int row = blockIdx.x * blockDim.x + threadIdx.x;
    if (row >= nrows) return;

    const float* xr = x + (size_t)row * TQ_D;

    float xs[TQ_D];
#pragma unroll
    for (int k = 0; k < TQ_D; k += 4) {
        float4 v = *reinterpret_cast<const float4*>(xr + k);
        xs[k] = v.x; xs[k + 1] = v.y; xs[k + 2] = v.z; xs[k + 3] = v.w;
    }

    // ---- numpy pairwise-8 (scalar path, n=64) sum of squares ----
    float r8[8];
#pragma unroll
    for (int j = 0; j < 8; ++j) r8[j] = xs[j] * xs[j];
#pragma unroll
    for (int i = 8; i < TQ_D; i += 8) {
#pragma unroll
        for (int j = 0; j < 8; ++j) {
            float t = xs[i + j] * xs[i + j];   // separate rounding (no fma)
            r8[j] = r8[j] + t;
        }
    }
    float ss = ((r8[0] + r8[1]) + (r8[2] + r8[3])) + ((r8[4] + r8[5]) + (r8[6] + r8[7]));

    float scale = (float)sqrt((double)ss);     // IEEE-correct fp32 sqrt
    scale = fmaxf(scale, 1e-8f);               // np.clip(norm, 1e-8, None)

    double sd = (double)scale;
#pragma unroll
    for (int k = 0; k < TQ_D; ++k)
        xs[k] = (float)((double)xs[k] / sd);   // IEEE RN fp32 division

    float cb[TQ_NLEV];
#pragma unroll
    for (int i = 0; i < TQ_NLEV; ++i) cb[i] = cbk[i];

    float acc[TQ_D];
#pragma unroll
    for (int k = 0; k < TQ_D; ++k) acc[k] = 0.0f;

#pragma unroll 2
    for (int j = 0; j < TQ_D; ++j) {
        const float* rj = R + j * TQ_D;        // wave-uniform -> s_loads

        // z_j: single sequential-k fma chain (sgemm micro-kernel order)
        float z = 0.0f;
#pragma unroll
        for (int k = 0; k < TQ_D; ++k)
            z = fmaf(xs[k], rj[k], z);

        // argmin |z - cb[i]|, first index wins ties (numpy argmin)
        float best = fabsf(z - cb[0]);
        int idx = 0;
#pragma unroll
        for (int i = 1; i < TQ_NLEV; ++i) {
            float d = fabsf(z - cb[i]);
            if (d < best) { best = d; idx = i; }
        }
        float zh = cb[idx];

        // reconstruction accumulate (fp32, order-insensitive at tolerance)
#pragma unroll
        for (int k = 0; k < TQ_D; ++k)
            acc[k] = fmaf(zh, rj[k], acc[k]);
    }

    float* orow = out + (size_t)row * TQ_D;
#pragma unroll
    for (int k = 0; k < TQ_D; k += 4) {
        float4 v;
        v.x = acc[k]     * scale;
        v.y = acc[k + 1] * scale;
        v.z = acc[k + 2] * scale;
        v.w = acc[k + 3] * scale;
        *reinterpret_cast<float4*>(orow + k) = v;
    }
}

extern "C" void kernel_launch(void* const* d_in, const int* in_sizes, int n_in,
                              void* d_out, int out_size, void* d_ws, size_t ws_size,
                              hipStream_t stream) {
    const float* x   = (const float*)d_in[0];
    const float* cbk = (const float*)d_in[1];
    const float* R   = (const float*)d_in[2];
    float* out = (float*)d_out;

    const int nrows = in_sizes[0] / TQ_D;      // 262144
    const int blocks = (nrows + 255) / 256;

    tq_f32<<<blocks, 256, 0, stream>>>(x, cbk, R, out, nrows);
}